// Round 13
// baseline (223.303 us; speedup 1.0000x reference)
//
#include <hip/hip_runtime.h>

#define LAT 64
#define ELLC 64       // ELL row capacity (deg ~ Poisson(32); overflow handled)
#define RB 128        // build rows per block (128x64x4B = 32KB LDS ELL stage)
#define RBSH 7
#define NBIN 400      // max bin buckets (256 rows each): N <= 102400
#define RBSHB 8       // bin bucket = 256 rows
#define STAGE 32      // per-bucket LDS ring depth (dwords); 400x32x4 = 51.2KB
#define RPT 8         // undirected edges cached per thread (256 x 1024 x 8 >= E)

// fp8 (e4m3) y-state, per-layer scale s_k = SC0 * RSC^k (round-0 notes).
// x0 bypasses fp8 (qacc init from fp32 embeds); last hop fused at query
// nodes only (R12: 3 full props + last_k, x4 never round-trips fp8).
// R13: bin_k's cost modeled as 3.2M scattered 4B store REQUESTS (~7cy/req/CU
// fabric floor, same currency as prop's gathers). Fix: LDS line-staging --
// per-bucket 32-dword rings keyed to GLOBAL offset (so flush lines are
// 16-dword aligned in LDS and global), full 64B lines flushed by 4-lane
// uint4 groups (1 coalesced request/line); <=15-dword head scattered during
// staging, tail at end. Store requests 3.2M -> ~1M. build_k reads 256-row
// bin buckets (2x read, 32MB) filtering by record bit 24.
#define SC0 64.0f
#define RSC 3.0f

typedef float f32x2 __attribute__((ext_vector_type(2)));

// ---------- phase 1: bin with LDS line-staged flush ----------
// Record: (r & 255) << 17 | c  (c < 131072). Bucket = r >> 8.
__global__ void __launch_bounds__(1024)
bin_k(const int* __restrict__ eu, const int* __restrict__ ei,
      int* __restrict__ gcur, unsigned int* __restrict__ bbuf,
      int2* __restrict__ ovf, int* __restrict__ ovfc,
      int E, int U, int nbuk, int cap, int ovf_cap) {
    __shared__ int lcnt[NBIN];       // per-bucket record count (monotonic)
    __shared__ int gflush[NBIN];     // next aligned GLOBAL flush offset
    __shared__ int rbase[NBIN];      // global reservation base
    __shared__ int okf[NBIN];        // bucket fits under cap
    __shared__ unsigned stage[NBIN * STAGE];   // ring, slot = (rbase+pos)&31
    for (int i = threadIdx.x; i < nbuk; i += blockDim.x) lcnt[i] = 0;
    __syncthreads();
    int tid = blockIdx.x * blockDim.x + threadIdx.x;
    int stride = gridDim.x * blockDim.x;
    int ru[RPT], rc[RPT];
    int ne = 0;
#pragma unroll
    for (int k = 0; k < RPT; ++k) {
        int d = tid + k * stride;
        if (d < E) {
            int u = eu[d], c = ei[d] + U;
            ru[k] = u; rc[k] = c; ne = k + 1;
            atomicAdd(&lcnt[u >> RBSHB], 1);
            atomicAdd(&lcnt[c >> RBSHB], 1);
        }
    }
    __syncthreads();
    for (int b = threadIdx.x; b < nbuk; b += blockDim.x) {
        int cb = lcnt[b];
        int rb = atomicAdd(&gcur[b], cb);
        rbase[b] = rb;
        okf[b] = (rb + cb <= cap);
        gflush[b] = (rb + 15) & ~15;   // first aligned line start
        lcnt[b] = 0;
    }
    __syncthreads();
    int gq = threadIdx.x >> 2, j = threadIdx.x & 3;
    // 16 half-phases: threads [0,512) stage on even h, [512,1024) on odd h.
    // Per phase <=1024 records over 391 buckets (lambda 2.6); ring margin
    // 32 - 15 unflushable = 17 >> lambda.
    for (int h = 0; h < 2 * RPT; ++h) {
        int k = h >> 1;
        if (k < ne && ((threadIdx.x >> 9) & 1) == (h & 1)) {
#pragma unroll
            for (int t = 0; t < 2; ++t) {
                int r = t ? rc[k] : ru[k];
                int c = t ? ru[k] : rc[k];
                int b = r >> RBSHB;
                unsigned w = ((unsigned)(r & 255) << 17) | (unsigned)c;
                int pos = atomicAdd(&lcnt[b], 1);
                if (okf[b]) {
                    int rb = rbase[b];
                    int gpos = rb + pos;
                    if (gpos < ((rb + 15) & ~15))           // unaligned head
                        bbuf[(size_t)b * cap + gpos] = w;   // scattered (<=15/bkt)
                    else
                        stage[(b << 5) + (gpos & (STAGE - 1))] = w;
                } else { int o = atomicAdd(ovfc, 1); if (o < ovf_cap) ovf[o] = make_int2(r, c); }
            }
        }
        __syncthreads();
        // flush full aligned 64B lines: 4 lanes x uint4 = 1 coalesced line
        for (int b = gq; b < nbuk; b += 256) {
            if (!okf[b]) continue;
            int end = rbase[b] + lcnt[b];
            int f = gflush[b];
            while (f + 16 <= end) {
                uint4 v = *(const uint4*)&stage[(b << 5) + (f & (STAGE - 1)) + (j << 2)];
                *(uint4*)&bbuf[(size_t)b * cap + f + (j << 2)] = v;
                f += 16;
            }
            if (j == 0) gflush[b] = f;
        }
        __syncthreads();
    }
    // tail (<16 dwords per bucket), scattered
    for (int b = gq; b < nbuk; b += 256) {
        if (!okf[b]) continue;
        int end = rbase[b] + lcnt[b];
        for (int g = gflush[b] + j; g < end; g += 4)
            bbuf[(size_t)b * cap + g] = stage[(b << 5) + (g & (STAGE - 1))];
    }
}

// ---------- phase 2: per-128-row-block LDS-staged ELL + dinv + y0 (fp8) ----
// Block b covers rows [b*128,(b+1)*128) = half of bin bucket b>>1; reads the
// full bucket (2x read) keeping records whose bit24 (r bit7) == b&1.
__global__ void __launch_bounds__(1024)
build_k(const unsigned int* __restrict__ bbuf, const int* __restrict__ gcur,
        int* __restrict__ cnt, int* __restrict__ colE, float* __restrict__ dinv,
        const float* __restrict__ ue, const float* __restrict__ ie,
        unsigned char* __restrict__ y0,
        int2* __restrict__ rovf, int* __restrict__ rovfc,
        int N, int U, int cap, int rovf_cap) {
    __shared__ int lcnt[RB];
    __shared__ float ldv[RB];
    __shared__ int ell[RB * ELLC];   // 32KB
    int b = blockIdx.x;
    int bb = b >> 1, sub = b & 1;
    for (int i = threadIdx.x; i < RB; i += blockDim.x) lcnt[i] = 0;
    for (int i = threadIdx.x; i < RB * ELLC; i += blockDim.x) ell[i] = 0;
    __syncthreads();
    int nb = min(gcur[bb], cap);
    const unsigned int* src = bbuf + (size_t)bb * cap;
    for (int e = threadIdx.x; e < nb; e += blockDim.x) {
        unsigned w = src[e];
        if ((int)((w >> 24) & 1) == sub) {
            int r7 = (int)(w >> 17) & 127;
            int c = (int)(w & 0x1FFFF);
            int pos = atomicAdd(&lcnt[r7], 1);
            if (pos < ELLC) ell[(r7 << 6) + pos] = c;
            else {
                int o = atomicAdd(rovfc, 1);
                if (o < rovf_cap) rovf[o] = make_int2((b << RBSH) + r7, c);
            }
        }
    }
    __syncthreads();
    for (int i = threadIdx.x; i < RB; i += blockDim.x) {
        int r = (b << RBSH) + i;
        if (r < N) {
            int d = lcnt[i];
            cnt[r] = d;
            float dv = (d > 0) ? rsqrtf((float)d) : 0.0f;
            dinv[r] = dv;            // spill rows fixed in fix_k
            ldv[i] = dv;
        }
    }
    __syncthreads();
    int r0 = b << RBSH;
    int rows = min(RB, N - r0);
    // fused y0 = fp8(SC0 * dinv * e0) for this block's rows (coalesced uint)
    for (int w = threadIdx.x; w < rows * 16; w += blockDim.x) {
        int i = w >> 4, j = w & 15;         // word j covers dims 4j..4j+3
        int r = r0 + i;
        const float* s = (r < U) ? (ue + (size_t)r * LAT) : (ie + (size_t)(r - U) * LAT);
        float4 f = ((const float4*)s)[j];
        float sc = SC0 * ldv[i];
        int p = __builtin_amdgcn_cvt_pk_fp8_f32(sc * f.x, sc * f.y, 0, false);
        p = __builtin_amdgcn_cvt_pk_fp8_f32(sc * f.z, sc * f.w, p, true);
        ((unsigned*)y0)[(size_t)r * 16 + j] = (unsigned)p;
    }
    // coalesced ELL writeout: rows*64 ints = rows*16 uint4 (pad included)
    uint4* dst = (uint4*)(colE + (size_t)r0 * ELLC);
    const uint4* lsrc = (const uint4*)ell;
    for (int w = threadIdx.x; w < rows * 16; w += blockDim.x)
        dst[w] = lsrc[w];
}

// bin-phase spill fix-up + dinv + y0 repair (expected ~0 entries). Single
// block; __syncthreads between phases so final cnt is seen.
__global__ void __launch_bounds__(1024)
fix_k(const int2* __restrict__ ovf, const int* __restrict__ ovfc,
      int* __restrict__ cnt, int* __restrict__ colE, float* __restrict__ dinv,
      const float* __restrict__ ue, const float* __restrict__ ie,
      unsigned char* __restrict__ y0,
      int2* __restrict__ rovf, int* __restrict__ rovfc,
      int ovf_cap, int rovf_cap, int U) {
    int n = min(*ovfc, ovf_cap);
    for (int i = threadIdx.x; i < n; i += blockDim.x) {
        int r = ovf[i].x, c = ovf[i].y;
        int pos = atomicAdd(&cnt[r], 1);
        if (pos < ELLC) colE[(size_t)r * ELLC + pos] = c;
        else { int o = atomicAdd(rovfc, 1); if (o < rovf_cap) rovf[o] = make_int2(r, c); }
    }
    __syncthreads();
    for (int i = threadIdx.x; i < n; i += blockDim.x) {
        int r = ovf[i].x;
        int d = cnt[r];
        dinv[r] = (d > 0) ? rsqrtf((float)d) : 0.0f;
    }
    __syncthreads();
    for (int w = threadIdx.x; w < n * 16; w += blockDim.x) {
        int o = w >> 4, j = w & 15;
        int r = ovf[o].x;
        const float* s = (r < U) ? (ue + (size_t)r * LAT) : (ie + (size_t)(r - U) * LAT);
        float4 f = ((const float4*)s)[j];
        float sc = SC0 * dinv[r];
        int p = __builtin_amdgcn_cvt_pk_fp8_f32(sc * f.x, sc * f.y, 0, false);
        p = __builtin_amdgcn_cvt_pk_fp8_f32(sc * f.z, sc * f.w, p, true);
        ((unsigned*)y0)[(size_t)r * 16 + j] = (unsigned)p;
    }
}

// ---------- propagation core ----------
// unpack one fp8 dword into 2 f32x2 accumulators (v_pk_add_f32 adds)
__device__ __forceinline__ void acc_word(unsigned w, f32x2* a) {
    a[0] += __builtin_amdgcn_cvt_pk_f32_fp8((int)w, false);
    a[1] += __builtin_amdgcn_cvt_pk_f32_fp8((int)w, true);
}

// Row waves: 4 nodes/wave, one per 16-lane group (see R4/R10 notes).
// Waves [NW, NW+2B): query gather (first: qacc = e0 exact fp32; else += x_k).
__global__ void __launch_bounds__(256, 8)
prop_h_k(const int* __restrict__ cnt, const int* __restrict__ colE,
         const float* __restrict__ dinv, const unsigned char* __restrict__ yin,
         unsigned char* __restrict__ yout,
         const int* __restrict__ users, const int* __restrict__ items,
         float* __restrict__ qacc,
         const float* __restrict__ ue, const float* __restrict__ ie,
         const int2* __restrict__ rovf, const int* __restrict__ rovfc,
         int rovf_cap, int B, int U, int first, int N, float inv_sin) {
    int wave = blockIdx.x * (blockDim.x >> 6) + (threadIdx.x >> 6);
    int lane = threadIdx.x & 63;
    int NW = (N + 3) >> 2;
    if (wave >= NW) {
        int qw = wave - NW;
        if (qw >= 2 * B) return;
        int node = (qw < B) ? users[qw] : (items[qw - B] + U);
        if (first) {
            float v = (node < U) ? ue[(size_t)node * LAT + lane]
                                 : ie[(size_t)(node - U) * LAT + lane];
            qacc[qw * LAT + lane] = v;
        } else {
            float di = dinv[node];
            unsigned bb = yin[(size_t)node * LAT + lane];      // one 64B line/wave
            f32x2 yv = __builtin_amdgcn_cvt_pk_f32_fp8((int)bb, false);
            qacc[qw * LAT + lane] += (di > 0.0f) ? yv[0] * inv_sin / di : 0.0f;
        }
        return;
    }
    int grp  = lane >> 4;          // group 0..3 -> node
    int gbase = lane & 48;         // grp*16
    int q  = (lane >> 2) & 3;      // neighbor slot within step
    int s4 = lane & 3;             // 16B chunk: dims 16*s4..16*s4+15
    int node = (wave << 2) + grp;
    int nadr = min(node, N - 1);   // clamped address for tail groups
    int len = (node < N) ? min(cnt[nadr], ELLC) : 0;
    const int* cp = colE + (size_t)nadr * ELLC;
    int wmax = len;
    wmax = max(wmax, __shfl_xor(wmax, 16));
    wmax = max(wmax, __shfl_xor(wmax, 32));
    wmax = __builtin_amdgcn_readfirstlane(wmax);
    int gl = lane & 15;
    int ca0 = cp[gl];
    int ca1 = (wmax > 16) ? cp[16 + gl] : 0;
    int ca2 = (wmax > 32) ? cp[32 + gl] : 0;
    int ca3 = (wmax > 48) ? cp[48 + gl] : 0;
    const uint4* y16 = (const uint4*)yin;

    f32x2 acc[8];
#pragma unroll
    for (int j = 0; j < 8; ++j) acc[j] = (f32x2)(0.f);

#pragma unroll
    for (int c = 0; c < 4; ++c) {
        int cac = (c == 0) ? ca0 : (c == 1) ? ca1 : (c == 2) ? ca2 : ca3;
#pragma unroll
        for (int si = 0; si < 4; ++si) {
            int s = (c << 2) + si;
            if ((s << 2) < wmax) {                 // wave-uniform guard
                int col = __shfl(cac, gbase + (si << 2) + q);   // 1 shfl / 4 nbrs
                if ((s << 2) + q < len) {          // per-lane validity
                    uint4 v = y16[(size_t)col * 4 + s4];
                    acc_word(v.x, acc + 0); acc_word(v.y, acc + 2);
                    acc_word(v.z, acc + 4); acc_word(v.w, acc + 6);
                }
            }
        }
    }
    // inline overflow epilogue (rovf static across layers; expected ~0)
    int novf = min(*rovfc, rovf_cap);
    for (int o = 0; o < novf; ++o) {
        int2 eo = rovf[o];
        if (eo.x == node && q == 0) {
            uint4 vv = y16[(size_t)eo.y * 4 + s4];
            acc_word(vv.x, acc + 0); acc_word(vv.y, acc + 2);
            acc_word(vv.z, acc + 4); acc_word(vv.w, acc + 6);
        }
    }
    // reduce-scatter across q (12 shfl): lane ends with dims d0..d0+3 summed,
    // d0 = 16*s4 + 8*b2 + 4*b3 = 4*widx.
    {
        bool hi = (lane & 4) != 0;
        f32x2 s[4], k[4];
#pragma unroll
        for (int i = 0; i < 4; ++i) { k[i] = hi ? acc[4 + i] : acc[i]; s[i] = hi ? acc[i] : acc[4 + i]; }
#pragma unroll
        for (int i = 0; i < 4; ++i) {
            f32x2 t;
            t.x = __shfl_xor(s[i].x, 4);
            t.y = __shfl_xor(s[i].y, 4);
            acc[i] = k[i] + t;
        }
    }
    {
        bool hi = (lane & 8) != 0;
        f32x2 s[2], k[2];
#pragma unroll
        for (int i = 0; i < 2; ++i) { k[i] = hi ? acc[2 + i] : acc[i]; s[i] = hi ? acc[i] : acc[2 + i]; }
#pragma unroll
        for (int i = 0; i < 2; ++i) {
            f32x2 t;
            t.x = __shfl_xor(s[i].x, 8);
            t.y = __shfl_xor(s[i].y, 8);
            acc[i] = k[i] + t;
        }
    }
    float dv = dinv[nadr];
    float f = dv * dv * RSC;               // fold out/in scale ratio into dinv^2
    int pk = __builtin_amdgcn_cvt_pk_fp8_f32(f * acc[0].x, f * acc[0].y, 0, false);
    pk = __builtin_amdgcn_cvt_pk_fp8_f32(f * acc[1].x, f * acc[1].y, pk, true);
    if (node < N) {
        int b2 = (lane >> 2) & 1, b3 = (lane >> 3) & 1;
        ((unsigned*)yout)[(size_t)node * 16 + (s4 << 2) + (b2 << 1) + b3] = (unsigned)pk;
    }
}

// ---------- last hop: query-node-only gather from y3; qacc += x3 + x4 ------
__global__ void __launch_bounds__(256, 8)
last_k(const int* __restrict__ cnt, const int* __restrict__ colE,
       const float* __restrict__ dinv, const unsigned char* __restrict__ y3,
       const int* __restrict__ users, const int* __restrict__ items,
       float* __restrict__ qacc,
       const int2* __restrict__ rovf, const int* __restrict__ rovfc,
       int rovf_cap, int B, int U, int N, float inv_s3) {
    int wave = blockIdx.x * (blockDim.x >> 6) + (threadIdx.x >> 6);
    int lane = threadIdx.x & 63;
    int grp  = lane >> 4;
    int gbase = lane & 48;
    int q  = (lane >> 2) & 3;
    int s4 = lane & 3;
    int e = (wave << 2) + grp;            // query entry
    int ecl = min(e, 2 * B - 1);
    int node = (ecl < B) ? users[ecl] : (items[ecl - B] + U);
    bool valid = (e < 2 * B);
    int len = valid ? min(cnt[node], ELLC) : 0;
    const int* cp = colE + (size_t)node * ELLC;
    int wmax = len;
    wmax = max(wmax, __shfl_xor(wmax, 16));
    wmax = max(wmax, __shfl_xor(wmax, 32));
    wmax = __builtin_amdgcn_readfirstlane(wmax);
    int gl = lane & 15;
    int ca0 = cp[gl];
    int ca1 = (wmax > 16) ? cp[16 + gl] : 0;
    int ca2 = (wmax > 32) ? cp[32 + gl] : 0;
    int ca3 = (wmax > 48) ? cp[48 + gl] : 0;
    const uint4* y16 = (const uint4*)y3;

    f32x2 acc[8];
#pragma unroll
    for (int j = 0; j < 8; ++j) acc[j] = (f32x2)(0.f);

#pragma unroll
    for (int c = 0; c < 4; ++c) {
        int cac = (c == 0) ? ca0 : (c == 1) ? ca1 : (c == 2) ? ca2 : ca3;
#pragma unroll
        for (int si = 0; si < 4; ++si) {
            int s = (c << 2) + si;
            if ((s << 2) < wmax) {
                int col = __shfl(cac, gbase + (si << 2) + q);
                if ((s << 2) + q < len) {
                    uint4 v = y16[(size_t)col * 4 + s4];
                    acc_word(v.x, acc + 0); acc_word(v.y, acc + 2);
                    acc_word(v.z, acc + 4); acc_word(v.w, acc + 6);
                }
            }
        }
    }
    int novf = min(*rovfc, rovf_cap);
    for (int o = 0; o < novf; ++o) {
        int2 eo = rovf[o];
        if (valid && eo.x == node && q == 0) {
            uint4 vv = y16[(size_t)eo.y * 4 + s4];
            acc_word(vv.x, acc + 0); acc_word(vv.y, acc + 2);
            acc_word(vv.z, acc + 4); acc_word(vv.w, acc + 6);
        }
    }
    {
        bool hi = (lane & 4) != 0;
        f32x2 s[4], k[4];
#pragma unroll
        for (int i = 0; i < 4; ++i) { k[i] = hi ? acc[4 + i] : acc[i]; s[i] = hi ? acc[i] : acc[4 + i]; }
#pragma unroll
        for (int i = 0; i < 4; ++i) {
            f32x2 t;
            t.x = __shfl_xor(s[i].x, 4);
            t.y = __shfl_xor(s[i].y, 4);
            acc[i] = k[i] + t;
        }
    }
    {
        bool hi = (lane & 8) != 0;
        f32x2 s[2], k[2];
#pragma unroll
        for (int i = 0; i < 2; ++i) { k[i] = hi ? acc[2 + i] : acc[i]; s[i] = hi ? acc[i] : acc[2 + i]; }
#pragma unroll
        for (int i = 0; i < 2; ++i) {
            f32x2 t;
            t.x = __shfl_xor(s[i].x, 8);
            t.y = __shfl_xor(s[i].y, 8);
            acc[i] = k[i] + t;
        }
    }
    int b2 = (lane >> 2) & 1, b3 = (lane >> 3) & 1;
    int widx = (s4 << 2) + (b2 << 1) + b3;
    float dv = dinv[node];
    float x4s = dv * inv_s3;                       // x4 = dv/s3 * sum
    float r3 = (dv > 0.f) ? inv_s3 / dv : 0.f;     // x3 = y3[n]/(s3*dv)
    unsigned w3 = ((const unsigned*)y3)[(size_t)node * 16 + widx];
    f32x2 lo3 = __builtin_amdgcn_cvt_pk_f32_fp8((int)w3, false);
    f32x2 hi3 = __builtin_amdgcn_cvt_pk_f32_fp8((int)w3, true);
    if (valid) {
        float4* qp = (float4*)(qacc + (size_t)e * LAT + (widx << 2));
        float4 old = *qp;
        old.x += x4s * acc[0].x + r3 * lo3[0];
        old.y += x4s * acc[0].y + r3 * lo3[1];
        old.z += x4s * acc[1].x + r3 * hi3[0];
        old.w += x4s * acc[1].y + r3 * hi3[1];
        *qp = old;
    }
}

// dot: gamma = <qacc_u, qacc_i> / 25
__global__ void dot_k(const float* __restrict__ qacc, float* __restrict__ out, int B) {
    int wave = blockIdx.x * (blockDim.x >> 6) + (threadIdx.x >> 6);
    int lane = threadIdx.x & 63;
    if (wave >= B) return;
    float au = qacc[(size_t)wave * LAT + lane];
    float ai = qacc[(size_t)(wave + B) * LAT + lane];
    float p = au * ai;
#pragma unroll
    for (int off = 32; off > 0; off >>= 1) p += __shfl_down(p, off);
    if (lane == 0) out[wave] = p * (1.0f / 25.0f);
}

extern "C" void kernel_launch(void* const* d_in, const int* in_sizes, int n_in,
                              void* d_out, int out_size, void* d_ws, size_t ws_size,
                              hipStream_t stream) {
    const float* ue = (const float*)d_in[0];
    const float* ie = (const float*)d_in[1];
    const int* edge = (const int*)d_in[2];
    const int* users = (const int*)d_in[3];
    const int* items = (const int*)d_in[4];

    const int U = in_sizes[0] / LAT;
    const int I = in_sizes[1] / LAT;
    const int N = U + I;
    const int E = in_sizes[2] / 2;
    const int B = in_sizes[3];
    const int* eu = edge;
    const int* ei = edge + E;

    const int nbuk = (N + 255) >> 8;                       // bin buckets (256 rows): 391
    const int nbld = (N + RB - 1) / RB;                    // build blocks (128 rows): 782
    const int cap = ((2 * E / nbuk) * 5 / 4 + 255) & ~255; // ~25% slack

    char* ws = (char*)d_ws;
    size_t off = 0;
    auto alloc = [&](size_t bytes) -> void* {
        void* p = ws + off;
        off += (bytes + 255) & ~(size_t)255;
        return p;
    };
    int*           cnt  = (int*)alloc((size_t)4 * N);
    float*         dinv = (float*)alloc((size_t)4 * N);
    int*           colE = (int*)alloc((size_t)4 * N * ELLC);     // 25.6 MB
    unsigned char* yA   = (unsigned char*)alloc((size_t)N * LAT); // 6.4 MB fp8
    unsigned char* yB   = (unsigned char*)alloc((size_t)N * LAT);
    float*         qacc = (float*)alloc((size_t)4 * 2 * B * LAT);
    unsigned*      bbuf = (unsigned*)alloc((size_t)4 * nbuk * cap);  // ~16 MB
    // gcur and ovfc adjacent -> single memset covers both
    size_t zoff = off;
    int*      gcur = (int*)alloc((size_t)4 * nbuk);
    int*      ovfc = (int*)alloc(256);   // 64 ints: [0]=bin spill, [16]=row ovf
    size_t zbytes = off - zoff;
    size_t remain = (ws_size > off + 256) ? (ws_size - off - 256) : 0;
    int ovf_cap = (int)min((size_t)131072, remain / (2 * sizeof(int2)));
    int2* ovf  = (int2*)alloc((size_t)ovf_cap * sizeof(int2));
    int2* rovf = (int2*)alloc((size_t)ovf_cap * sizeof(int2));
    // rovfc = ovfc + 16 INTS (byte 64): inside the zeroed 256-byte block.
    int* rovfc = ovfc + 16;

    hipError_t _e = hipMemsetAsync(gcur, 0, zbytes, stream); (void)_e;

    const int tb = 256;

    // 256 blocks x 1024 thr x RPT 8 = 2.1M >= E undirected edges
    bin_k<<<256, 1024, 0, stream>>>(eu, ei, gcur, bbuf, ovf, ovfc, E, U, nbuk, cap, ovf_cap);
    build_k<<<nbld, 1024, 0, stream>>>(bbuf, gcur, cnt, colE, dinv, ue, ie, yA,
                                       rovf, rovfc, N, U, cap, ovf_cap);
    fix_k<<<1, 1024, 0, stream>>>(ovf, ovfc, cnt, colE, dinv, ue, ie, yA,
                                  rovf, rovfc, ovf_cap, ovf_cap, U);

    const int wpb = tb / 64;
    const int NW = (N + 3) >> 2;               // 4 nodes per row-wave
    int pgrid = (NW + 2 * B + wpb - 1) / wpb;  // row waves + fused query waves

    // 3 full propagations: y0->y1->y2->y3; qacc accumulates x0+x1+x2
    unsigned char* yin = yA;
    unsigned char* yout = yB;
    float s_in = SC0;
    for (int layer = 0; layer < 3; ++layer) {
        prop_h_k<<<pgrid, tb, 0, stream>>>(cnt, colE, dinv, yin, yout,
                                           users, items, qacc, ue, ie, rovf, rovfc,
                                           ovf_cap, B, U, layer == 0 ? 1 : 0, N,
                                           1.0f / s_in);
        s_in *= RSC;
        unsigned char* tmp = yin; yin = yout; yout = tmp;
    }
    // yin now = y3, scale s_in = s3 = SC0*RSC^3

    // last hop only at query nodes: qacc += x3 + x4 (x4 in fp32)
    int lwaves = (2 * B + 3) >> 2;             // 4 entries per wave
    last_k<<<(lwaves + wpb - 1) / wpb, tb, 0, stream>>>(cnt, colE, dinv, yin,
                                                        users, items, qacc,
                                                        rovf, rovfc, ovf_cap,
                                                        B, U, N, 1.0f / s_in);

    dot_k<<<(B + wpb - 1) / wpb, tb, 0, stream>>>(qacc, (float*)d_out, B);
}

// Round 14
// 218.012 us; speedup vs baseline: 1.0243x; 1.0243x over previous
//
#include <hip/hip_runtime.h>

#define LAT 64
#define ELLC 64       // ELL row capacity (deg ~ Poisson(32); overflow handled)
#define RB 128        // rows per bucket (128x64x4B = 32KB LDS ELL stage)
#define RBSH 7
#define MAXBUK 1024   // static LDS sizing; nbuk = ceil(N/128) = 782 for N=100k
#define RPT 8         // undirected edges cached per thread (256 x 1024 x 8 >= E)

// fp8 (e4m3) y-state, per-layer scale s_k = SC0 * RSC^k (round-0 notes).
// x0 (dominant output term) bypasses fp8: qacc initialized from fp32 embeds.
// R12 (best, 218.6us): 3 full props + query-only last hop (x4 never
// round-trips fp8); R6 reservation binning + LDS-staged ELL build.
// R13 post-mortem: LDS line-staged bin flush REGRESSED (+4.7us) -- second
// falsification of "bin is store-bound"; residual bin cost is LDS atomics +
// reservation, already near-optimal in this design. This is the R12 revert.
#define SC0 64.0f
#define RSC 3.0f

typedef float f32x2 __attribute__((ext_vector_type(2)));

// ---------- phase 1: bin directed edges by row-bucket (single edge read) -----
// Packed word: (r & 127) << 17 | c   (needs N <= 131072).
__global__ void __launch_bounds__(1024)
bin_k(const int* __restrict__ eu, const int* __restrict__ ei,
      int* __restrict__ gcur, unsigned int* __restrict__ bbuf,
      int2* __restrict__ ovf, int* __restrict__ ovfc,
      int E, int U, int nbuk, int cap, int ovf_cap) {
    __shared__ int lcnt[MAXBUK];
    __shared__ int lbase[MAXBUK];
    for (int i = threadIdx.x; i < nbuk; i += blockDim.x) lcnt[i] = 0;
    __syncthreads();
    int tid = blockIdx.x * blockDim.x + threadIdx.x;
    int stride = gridDim.x * blockDim.x;
    int ru[RPT], rc[RPT];
    int ne = 0;
#pragma unroll
    for (int k = 0; k < RPT; ++k) {
        int d = tid + k * stride;
        if (d < E) {
            int u = eu[d], c = ei[d] + U;
            ru[k] = u; rc[k] = c; ne = k + 1;
            atomicAdd(&lcnt[u >> RBSH], 1);   // user-side row
            atomicAdd(&lcnt[c >> RBSH], 1);   // item-side row
        }
    }
    __syncthreads();
    for (int b = threadIdx.x; b < nbuk; b += blockDim.x)
        lbase[b] = atomicAdd(&gcur[b], lcnt[b]);      // global reservation
    __syncthreads();
#pragma unroll
    for (int k = 0; k < RPT; ++k) {
        if (k < ne) {
            int u = ru[k], c = rc[k];
            int b = u >> RBSH;
            int pos = atomicAdd(&lbase[b], 1);
            if (pos < cap)
                bbuf[(size_t)b * cap + pos] = ((unsigned)(u & (RB - 1)) << 17) | (unsigned)c;
            else { int o = atomicAdd(ovfc, 1); if (o < ovf_cap) ovf[o] = make_int2(u, c); }
            b = c >> RBSH;
            pos = atomicAdd(&lbase[b], 1);
            if (pos < cap)
                bbuf[(size_t)b * cap + pos] = ((unsigned)(c & (RB - 1)) << 17) | (unsigned)u;
            else { int o = atomicAdd(ovfc, 1); if (o < ovf_cap) ovf[o] = make_int2(c, u); }
        }
    }
}

// ---------- phase 2: per-bucket LDS-staged ELL + dinv + fused y0 (fp8) ------
__global__ void __launch_bounds__(1024)
build_k(const unsigned int* __restrict__ bbuf, const int* __restrict__ gcur,
        int* __restrict__ cnt, int* __restrict__ colE, float* __restrict__ dinv,
        const float* __restrict__ ue, const float* __restrict__ ie,
        unsigned char* __restrict__ y0,
        int2* __restrict__ rovf, int* __restrict__ rovfc,
        int N, int U, int cap, int rovf_cap) {
    __shared__ int lcnt[RB];
    __shared__ float ldv[RB];
    __shared__ int ell[RB * ELLC];   // 32KB
    int b = blockIdx.x;
    for (int i = threadIdx.x; i < RB; i += blockDim.x) lcnt[i] = 0;
    for (int i = threadIdx.x; i < RB * ELLC; i += blockDim.x) ell[i] = 0;
    __syncthreads();
    int nb = min(gcur[b], cap);
    const unsigned int* src = bbuf + (size_t)b * cap;
    for (int e = threadIdx.x; e < nb; e += blockDim.x) {
        unsigned w = src[e];
        int r7 = (int)(w >> 17);
        int c = (int)(w & 0x1FFFF);
        int pos = atomicAdd(&lcnt[r7], 1);
        if (pos < ELLC) ell[(r7 << 6) + pos] = c;
        else {
            int o = atomicAdd(rovfc, 1);
            if (o < rovf_cap) rovf[o] = make_int2((b << RBSH) + r7, c);
        }
    }
    __syncthreads();
    for (int i = threadIdx.x; i < RB; i += blockDim.x) {
        int r = (b << RBSH) + i;
        if (r < N) {
            int d = lcnt[i];
            cnt[r] = d;
            float dv = (d > 0) ? rsqrtf((float)d) : 0.0f;
            dinv[r] = dv;            // spill rows fixed in fix_k
            ldv[i] = dv;
        }
    }
    __syncthreads();
    int r0 = b << RBSH;
    int rows = min(RB, N - r0);
    // fused y0 = fp8(SC0 * dinv * e0) for this bucket's rows (coalesced uint)
    for (int w = threadIdx.x; w < rows * 16; w += blockDim.x) {
        int i = w >> 4, j = w & 15;         // word j covers dims 4j..4j+3
        int r = r0 + i;
        const float* s = (r < U) ? (ue + (size_t)r * LAT) : (ie + (size_t)(r - U) * LAT);
        float4 f = ((const float4*)s)[j];
        float sc = SC0 * ldv[i];
        int p = __builtin_amdgcn_cvt_pk_fp8_f32(sc * f.x, sc * f.y, 0, false);
        p = __builtin_amdgcn_cvt_pk_fp8_f32(sc * f.z, sc * f.w, p, true);
        ((unsigned*)y0)[(size_t)r * 16 + j] = (unsigned)p;
    }
    // coalesced ELL writeout: rows*64 ints = rows*16 uint4 (pad included)
    uint4* dst = (uint4*)(colE + (size_t)r0 * ELLC);
    const uint4* lsrc = (const uint4*)ell;
    for (int w = threadIdx.x; w < rows * 16; w += blockDim.x)
        dst[w] = lsrc[w];
}

// bin-phase spill fix-up + dinv + y0 repair (expected ~0 entries). Single
// block; __syncthreads between phases so final cnt is seen.
__global__ void __launch_bounds__(1024)
fix_k(const int2* __restrict__ ovf, const int* __restrict__ ovfc,
      int* __restrict__ cnt, int* __restrict__ colE, float* __restrict__ dinv,
      const float* __restrict__ ue, const float* __restrict__ ie,
      unsigned char* __restrict__ y0,
      int2* __restrict__ rovf, int* __restrict__ rovfc,
      int ovf_cap, int rovf_cap, int U) {
    int n = min(*ovfc, ovf_cap);
    for (int i = threadIdx.x; i < n; i += blockDim.x) {
        int r = ovf[i].x, c = ovf[i].y;
        int pos = atomicAdd(&cnt[r], 1);
        if (pos < ELLC) colE[(size_t)r * ELLC + pos] = c;
        else { int o = atomicAdd(rovfc, 1); if (o < rovf_cap) rovf[o] = make_int2(r, c); }
    }
    __syncthreads();
    for (int i = threadIdx.x; i < n; i += blockDim.x) {
        int r = ovf[i].x;
        int d = cnt[r];
        dinv[r] = (d > 0) ? rsqrtf((float)d) : 0.0f;
    }
    __syncthreads();
    for (int w = threadIdx.x; w < n * 16; w += blockDim.x) {
        int o = w >> 4, j = w & 15;
        int r = ovf[o].x;
        const float* s = (r < U) ? (ue + (size_t)r * LAT) : (ie + (size_t)(r - U) * LAT);
        float4 f = ((const float4*)s)[j];
        float sc = SC0 * dinv[r];
        int p = __builtin_amdgcn_cvt_pk_fp8_f32(sc * f.x, sc * f.y, 0, false);
        p = __builtin_amdgcn_cvt_pk_fp8_f32(sc * f.z, sc * f.w, p, true);
        ((unsigned*)y0)[(size_t)r * 16 + j] = (unsigned)p;
    }
}

// ---------- propagation core ----------
// unpack one fp8 dword into 2 f32x2 accumulators (v_pk_add_f32 adds)
__device__ __forceinline__ void acc_word(unsigned w, f32x2* a) {
    a[0] += __builtin_amdgcn_cvt_pk_f32_fp8((int)w, false);
    a[1] += __builtin_amdgcn_cvt_pk_f32_fp8((int)w, true);
}

// Row waves: 4 nodes/wave, one per 16-lane group (see R4/R10 notes).
// Waves [NW, NW+2B): query gather (first: qacc = e0 exact fp32; else += x_k).
__global__ void __launch_bounds__(256, 8)
prop_h_k(const int* __restrict__ cnt, const int* __restrict__ colE,
         const float* __restrict__ dinv, const unsigned char* __restrict__ yin,
         unsigned char* __restrict__ yout,
         const int* __restrict__ users, const int* __restrict__ items,
         float* __restrict__ qacc,
         const float* __restrict__ ue, const float* __restrict__ ie,
         const int2* __restrict__ rovf, const int* __restrict__ rovfc,
         int rovf_cap, int B, int U, int first, int N, float inv_sin) {
    int wave = blockIdx.x * (blockDim.x >> 6) + (threadIdx.x >> 6);
    int lane = threadIdx.x & 63;
    int NW = (N + 3) >> 2;
    if (wave >= NW) {
        int qw = wave - NW;
        if (qw >= 2 * B) return;
        int node = (qw < B) ? users[qw] : (items[qw - B] + U);
        if (first) {
            float v = (node < U) ? ue[(size_t)node * LAT + lane]
                                 : ie[(size_t)(node - U) * LAT + lane];
            qacc[qw * LAT + lane] = v;
        } else {
            float di = dinv[node];
            unsigned bb = yin[(size_t)node * LAT + lane];      // one 64B line/wave
            f32x2 yv = __builtin_amdgcn_cvt_pk_f32_fp8((int)bb, false);
            qacc[qw * LAT + lane] += (di > 0.0f) ? yv[0] * inv_sin / di : 0.0f;
        }
        return;
    }
    int grp  = lane >> 4;          // group 0..3 -> node
    int gbase = lane & 48;         // grp*16
    int q  = (lane >> 2) & 3;      // neighbor slot within step
    int s4 = lane & 3;             // 16B chunk: dims 16*s4..16*s4+15
    int node = (wave << 2) + grp;
    int nadr = min(node, N - 1);   // clamped address for tail groups
    int len = (node < N) ? min(cnt[nadr], ELLC) : 0;
    const int* cp = colE + (size_t)nadr * ELLC;
    int wmax = len;
    wmax = max(wmax, __shfl_xor(wmax, 16));
    wmax = max(wmax, __shfl_xor(wmax, 32));
    wmax = __builtin_amdgcn_readfirstlane(wmax);
    int gl = lane & 15;
    int ca0 = cp[gl];
    int ca1 = (wmax > 16) ? cp[16 + gl] : 0;
    int ca2 = (wmax > 32) ? cp[32 + gl] : 0;
    int ca3 = (wmax > 48) ? cp[48 + gl] : 0;
    const uint4* y16 = (const uint4*)yin;

    f32x2 acc[8];
#pragma unroll
    for (int j = 0; j < 8; ++j) acc[j] = (f32x2)(0.f);

#pragma unroll
    for (int c = 0; c < 4; ++c) {
        int cac = (c == 0) ? ca0 : (c == 1) ? ca1 : (c == 2) ? ca2 : ca3;
#pragma unroll
        for (int si = 0; si < 4; ++si) {
            int s = (c << 2) + si;
            if ((s << 2) < wmax) {                 // wave-uniform guard
                int col = __shfl(cac, gbase + (si << 2) + q);   // 1 shfl / 4 nbrs
                if ((s << 2) + q < len) {          // per-lane validity
                    uint4 v = y16[(size_t)col * 4 + s4];
                    acc_word(v.x, acc + 0); acc_word(v.y, acc + 2);
                    acc_word(v.z, acc + 4); acc_word(v.w, acc + 6);
                }
            }
        }
    }
    // inline overflow epilogue (rovf static across layers; expected ~0)
    int novf = min(*rovfc, rovf_cap);
    for (int o = 0; o < novf; ++o) {
        int2 eo = rovf[o];
        if (eo.x == node && q == 0) {
            uint4 vv = y16[(size_t)eo.y * 4 + s4];
            acc_word(vv.x, acc + 0); acc_word(vv.y, acc + 2);
            acc_word(vv.z, acc + 4); acc_word(vv.w, acc + 6);
        }
    }
    // reduce-scatter across q (12 shfl): lane ends with dims d0..d0+3 summed,
    // d0 = 16*s4 + 8*b2 + 4*b3 = 4*widx.
    {
        bool hi = (lane & 4) != 0;
        f32x2 s[4], k[4];
#pragma unroll
        for (int i = 0; i < 4; ++i) { k[i] = hi ? acc[4 + i] : acc[i]; s[i] = hi ? acc[i] : acc[4 + i]; }
#pragma unroll
        for (int i = 0; i < 4; ++i) {
            f32x2 t;
            t.x = __shfl_xor(s[i].x, 4);
            t.y = __shfl_xor(s[i].y, 4);
            acc[i] = k[i] + t;
        }
    }
    {
        bool hi = (lane & 8) != 0;
        f32x2 s[2], k[2];
#pragma unroll
        for (int i = 0; i < 2; ++i) { k[i] = hi ? acc[2 + i] : acc[i]; s[i] = hi ? acc[i] : acc[2 + i]; }
#pragma unroll
        for (int i = 0; i < 2; ++i) {
            f32x2 t;
            t.x = __shfl_xor(s[i].x, 8);
            t.y = __shfl_xor(s[i].y, 8);
            acc[i] = k[i] + t;
        }
    }
    float dv = dinv[nadr];
    float f = dv * dv * RSC;               // fold out/in scale ratio into dinv^2
    int pk = __builtin_amdgcn_cvt_pk_fp8_f32(f * acc[0].x, f * acc[0].y, 0, false);
    pk = __builtin_amdgcn_cvt_pk_fp8_f32(f * acc[1].x, f * acc[1].y, pk, true);
    if (node < N) {
        int b2 = (lane >> 2) & 1, b3 = (lane >> 3) & 1;
        ((unsigned*)yout)[(size_t)node * 16 + (s4 << 2) + (b2 << 1) + b3] = (unsigned)pk;
    }
}

// ---------- last hop: query-node-only gather from y3; qacc += x3 + x4 ------
// Same 16-lane-group gather structure as prop, but over the 2B query entries
// (4 entries/wave) instead of all N nodes. x4 = dinv_n * sum(y3[c]) / s3 is
// accumulated in fp32 (no fp8 roundtrip). x3 = y3[n] / (s3 * dinv_n).
__global__ void __launch_bounds__(256, 8)
last_k(const int* __restrict__ cnt, const int* __restrict__ colE,
       const float* __restrict__ dinv, const unsigned char* __restrict__ y3,
       const int* __restrict__ users, const int* __restrict__ items,
       float* __restrict__ qacc,
       const int2* __restrict__ rovf, const int* __restrict__ rovfc,
       int rovf_cap, int B, int U, int N, float inv_s3) {
    int wave = blockIdx.x * (blockDim.x >> 6) + (threadIdx.x >> 6);
    int lane = threadIdx.x & 63;
    int grp  = lane >> 4;
    int gbase = lane & 48;
    int q  = (lane >> 2) & 3;
    int s4 = lane & 3;
    int e = (wave << 2) + grp;            // query entry
    int ecl = min(e, 2 * B - 1);
    int node = (ecl < B) ? users[ecl] : (items[ecl - B] + U);
    bool valid = (e < 2 * B);
    int len = valid ? min(cnt[node], ELLC) : 0;
    const int* cp = colE + (size_t)node * ELLC;
    int wmax = len;
    wmax = max(wmax, __shfl_xor(wmax, 16));
    wmax = max(wmax, __shfl_xor(wmax, 32));
    wmax = __builtin_amdgcn_readfirstlane(wmax);
    int gl = lane & 15;
    int ca0 = cp[gl];
    int ca1 = (wmax > 16) ? cp[16 + gl] : 0;
    int ca2 = (wmax > 32) ? cp[32 + gl] : 0;
    int ca3 = (wmax > 48) ? cp[48 + gl] : 0;
    const uint4* y16 = (const uint4*)y3;

    f32x2 acc[8];
#pragma unroll
    for (int j = 0; j < 8; ++j) acc[j] = (f32x2)(0.f);

#pragma unroll
    for (int c = 0; c < 4; ++c) {
        int cac = (c == 0) ? ca0 : (c == 1) ? ca1 : (c == 2) ? ca2 : ca3;
#pragma unroll
        for (int si = 0; si < 4; ++si) {
            int s = (c << 2) + si;
            if ((s << 2) < wmax) {
                int col = __shfl(cac, gbase + (si << 2) + q);
                if ((s << 2) + q < len) {
                    uint4 v = y16[(size_t)col * 4 + s4];
                    acc_word(v.x, acc + 0); acc_word(v.y, acc + 2);
                    acc_word(v.z, acc + 4); acc_word(v.w, acc + 6);
                }
            }
        }
    }
    int novf = min(*rovfc, rovf_cap);
    for (int o = 0; o < novf; ++o) {
        int2 eo = rovf[o];
        if (valid && eo.x == node && q == 0) {
            uint4 vv = y16[(size_t)eo.y * 4 + s4];
            acc_word(vv.x, acc + 0); acc_word(vv.y, acc + 2);
            acc_word(vv.z, acc + 4); acc_word(vv.w, acc + 6);
        }
    }
    {
        bool hi = (lane & 4) != 0;
        f32x2 s[4], k[4];
#pragma unroll
        for (int i = 0; i < 4; ++i) { k[i] = hi ? acc[4 + i] : acc[i]; s[i] = hi ? acc[i] : acc[4 + i]; }
#pragma unroll
        for (int i = 0; i < 4; ++i) {
            f32x2 t;
            t.x = __shfl_xor(s[i].x, 4);
            t.y = __shfl_xor(s[i].y, 4);
            acc[i] = k[i] + t;
        }
    }
    {
        bool hi = (lane & 8) != 0;
        f32x2 s[2], k[2];
#pragma unroll
        for (int i = 0; i < 2; ++i) { k[i] = hi ? acc[2 + i] : acc[i]; s[i] = hi ? acc[i] : acc[2 + i]; }
#pragma unroll
        for (int i = 0; i < 2; ++i) {
            f32x2 t;
            t.x = __shfl_xor(s[i].x, 8);
            t.y = __shfl_xor(s[i].y, 8);
            acc[i] = k[i] + t;
        }
    }
    // lane holds dims d0..d0+3 of sum(y3[c]); d0 = 4*widx
    int b2 = (lane >> 2) & 1, b3 = (lane >> 3) & 1;
    int widx = (s4 << 2) + (b2 << 1) + b3;
    float dv = dinv[node];
    float x4s = dv * inv_s3;                       // x4 = dv/s3 * sum
    float r3 = (dv > 0.f) ? inv_s3 / dv : 0.f;     // x3 = y3[n]/(s3*dv)
    unsigned w3 = ((const unsigned*)y3)[(size_t)node * 16 + widx];
    f32x2 lo3 = __builtin_amdgcn_cvt_pk_f32_fp8((int)w3, false);
    f32x2 hi3 = __builtin_amdgcn_cvt_pk_f32_fp8((int)w3, true);
    if (valid) {
        float4* qp = (float4*)(qacc + (size_t)e * LAT + (widx << 2));
        float4 old = *qp;
        old.x += x4s * acc[0].x + r3 * lo3[0];
        old.y += x4s * acc[0].y + r3 * lo3[1];
        old.z += x4s * acc[1].x + r3 * hi3[0];
        old.w += x4s * acc[1].y + r3 * hi3[1];
        *qp = old;
    }
}

// dot: gamma = <qacc_u, qacc_i> / 25
__global__ void dot_k(const float* __restrict__ qacc, float* __restrict__ out, int B) {
    int wave = blockIdx.x * (blockDim.x >> 6) + (threadIdx.x >> 6);
    int lane = threadIdx.x & 63;
    if (wave >= B) return;
    float au = qacc[(size_t)wave * LAT + lane];
    float ai = qacc[(size_t)(wave + B) * LAT + lane];
    float p = au * ai;
#pragma unroll
    for (int off = 32; off > 0; off >>= 1) p += __shfl_down(p, off);
    if (lane == 0) out[wave] = p * (1.0f / 25.0f);
}

extern "C" void kernel_launch(void* const* d_in, const int* in_sizes, int n_in,
                              void* d_out, int out_size, void* d_ws, size_t ws_size,
                              hipStream_t stream) {
    const float* ue = (const float*)d_in[0];
    const float* ie = (const float*)d_in[1];
    const int* edge = (const int*)d_in[2];
    const int* users = (const int*)d_in[3];
    const int* items = (const int*)d_in[4];

    const int U = in_sizes[0] / LAT;
    const int I = in_sizes[1] / LAT;
    const int N = U + I;
    const int E = in_sizes[2] / 2;
    const int B = in_sizes[3];
    const int* eu = edge;
    const int* ei = edge + E;

    const int nbuk = (N + RB - 1) / RB;                    // 782 for N=100k
    const int cap = ((2 * E / nbuk) * 5 / 4 + 255) & ~255; // ~25% slack

    char* ws = (char*)d_ws;
    size_t off = 0;
    auto alloc = [&](size_t bytes) -> void* {
        void* p = ws + off;
        off += (bytes + 255) & ~(size_t)255;
        return p;
    };
    int*           cnt  = (int*)alloc((size_t)4 * N);
    float*         dinv = (float*)alloc((size_t)4 * N);
    int*           colE = (int*)alloc((size_t)4 * N * ELLC);     // 25.6 MB
    unsigned char* yA   = (unsigned char*)alloc((size_t)N * LAT); // 6.4 MB fp8
    unsigned char* yB   = (unsigned char*)alloc((size_t)N * LAT);
    float*         qacc = (float*)alloc((size_t)4 * 2 * B * LAT);
    unsigned*      bbuf = (unsigned*)alloc((size_t)4 * nbuk * cap);  // ~16 MB
    // gcur and ovfc adjacent -> single memset covers both
    size_t zoff = off;
    int*      gcur = (int*)alloc((size_t)4 * nbuk);
    int*      ovfc = (int*)alloc(256);   // 64 ints: [0]=bin spill, [16]=row ovf
    size_t zbytes = off - zoff;
    size_t remain = (ws_size > off + 256) ? (ws_size - off - 256) : 0;
    int ovf_cap = (int)min((size_t)131072, remain / (2 * sizeof(int2)));
    int2* ovf  = (int2*)alloc((size_t)ovf_cap * sizeof(int2));
    int2* rovf = (int2*)alloc((size_t)ovf_cap * sizeof(int2));
    // rovfc = ovfc + 16 INTS (byte 64): inside the zeroed 256-byte block.
    int* rovfc = ovfc + 16;

    hipError_t _e = hipMemsetAsync(gcur, 0, zbytes, stream); (void)_e;

    const int tb = 256;

    // 256 blocks x 1024 thr x RPT 8 = 2.1M >= E undirected edges
    bin_k<<<256, 1024, 0, stream>>>(eu, ei, gcur, bbuf, ovf, ovfc, E, U, nbuk, cap, ovf_cap);
    build_k<<<nbuk, 1024, 0, stream>>>(bbuf, gcur, cnt, colE, dinv, ue, ie, yA,
                                       rovf, rovfc, N, U, cap, ovf_cap);
    fix_k<<<1, 1024, 0, stream>>>(ovf, ovfc, cnt, colE, dinv, ue, ie, yA,
                                  rovf, rovfc, ovf_cap, ovf_cap, U);

    const int wpb = tb / 64;
    const int NW = (N + 3) >> 2;               // 4 nodes per row-wave
    int pgrid = (NW + 2 * B + wpb - 1) / wpb;  // row waves + fused query waves

    // 3 full propagations: y0->y1->y2->y3; qacc accumulates x0+x1+x2
    unsigned char* yin = yA;
    unsigned char* yout = yB;
    float s_in = SC0;
    for (int layer = 0; layer < 3; ++layer) {
        prop_h_k<<<pgrid, tb, 0, stream>>>(cnt, colE, dinv, yin, yout,
                                           users, items, qacc, ue, ie, rovf, rovfc,
                                           ovf_cap, B, U, layer == 0 ? 1 : 0, N,
                                           1.0f / s_in);
        s_in *= RSC;
        unsigned char* tmp = yin; yin = yout; yout = tmp;
    }
    // yin now = y3, scale s_in = s3 = SC0*RSC^3

    // last hop only at query nodes: qacc += x3 + x4 (x4 in fp32)
    int lwaves = (2 * B + 3) >> 2;             // 4 entries per wave
    last_k<<<(lwaves + wpb - 1) / wpb, tb, 0, stream>>>(cnt, colE, dinv, yin,
                                                        users, items, qacc,
                                                        rovf, rovfc, ovf_cap,
                                                        B, U, N, 1.0f / s_in);

    dot_k<<<(B + wpb - 1) / wpb, tb, 0, stream>>>(qacc, (float*)d_out, B);
}